// Round 6
// baseline (579.860 us; speedup 1.0000x reference)
//
#include <hip/hip_runtime.h>

#define D 128
#define CAP 32
#define EPT 2          // edges per thread in bucket blocks
#define NEG_SLOPE 0.01f

typedef float v4f __attribute__((ext_vector_type(4)));
typedef short short8 __attribute__((ext_vector_type(8)));

static __device__ __forceinline__ short f2bf(float f) {
    unsigned u = __float_as_uint(f);
    unsigned r = (u + 0x7fffu + ((u >> 16) & 1u)) >> 16;   // round-nearest-even
    return (short)r;
}
static __device__ __forceinline__ float bflo(unsigned u) { return __uint_as_float(u << 16); }
static __device__ __forceinline__ float bfhi(unsigned u) { return __uint_as_float(u & 0xffff0000u); }
static __device__ __forceinline__ unsigned packbf(float x, float y) {
    return (unsigned)(unsigned short)f2bf(x) | ((unsigned)(unsigned short)f2bf(y) << 16);
}

// -------- fused, block-specialized: bucket blocks + conv blocks ------------
__global__ __launch_bounds__(256) void convbucket_kernel(const float* __restrict__ feat,
                                                         const float* __restrict__ W1,
                                                         const float* __restrict__ W2,
                                                         const int* __restrict__ tgt,
                                                         const int* __restrict__ nbr,
                                                         const float* __restrict__ vals,
                                                         unsigned* __restrict__ featbf,
                                                         short* __restrict__ Wbf,
                                                         int* __restrict__ deg,
                                                         unsigned* __restrict__ edata,
                                                         int4* __restrict__ ovf,
                                                         int* __restrict__ ovf_cnt,
                                                         int nQuads, int E, int nbB) {
    if ((int)blockIdx.x < nbB) {
        // ---- bucket specialist: entry = (nbr<<16) | bf16(val) ----
        int base = (blockIdx.x * 256 + threadIdx.x) * EPT;
#pragma unroll
        for (int k = 0; k < EPT; k++) {
            int e = base + k;
            if (e < E) {
                int   t = __builtin_nontemporal_load(&tgt[e]);
                int   n = __builtin_nontemporal_load(&nbr[e]);
                float v = __builtin_nontemporal_load(&vals[e]);
                int slot = atomicAdd(&deg[t], 1);
                if (slot < CAP) {
                    unsigned ent = ((unsigned)n << 16) |
                                   (unsigned)(unsigned short)f2bf(v);
                    edata[((unsigned)t << 5) + slot] = ent;
                } else {
                    int o = atomicAdd(ovf_cnt, 1);
                    int4 ov;
                    ov.x = t;
                    ov.y = n;
                    ov.z = __float_as_int(v);
                    ov.w = 0;
                    ovf[o] = ov;
                }
            }
        }
    } else {
        // ---- conv specialist: float4 in, 2x packed bf16 out ----
        int i = (blockIdx.x - nbB) * 256 + threadIdx.x;
        if (i < nQuads) {
            v4f f = __builtin_nontemporal_load((const v4f*)feat + i);
            uint2 p;
            p.x = packbf(f.x, f.y);
            p.y = packbf(f.z, f.w);
            ((uint2*)featbf)[i] = p;
        }
        if (i < D * D) {
            Wbf[i]         = f2bf(W1[i]);
            Wbf[D * D + i] = f2bf(W2[i]);
        }
    }
}

// -------- edge-balanced fused gather + dual-GEMM + bias + leaky relu -------
// One 512-thread block per 16-node tile:
//  p0: zero accum planes (single contiguous array -- in-bounds), load degrees
//  p1: prefix-sum clamped degrees; build compact (node<<5|slot) entry list
//  p2: 8 waves drain the entry list round-robin (batches of 8, 8 rows in
//      flight), accumulating val*feat[nbr] into LDS f32 planes via ds_add
//      (lo/hi split planes => 2-way banks, free). Perfect intra-block
//      balance, zero padded-slot waste.
//  p3: rare overflow (deg>CAP) fixup from the compact global list
//  p4: pack X1=f+h, X2=f*h as bf16 into XOR-swizzled sX
//  p5: GEMM: wave w = output col-block w; A from sX, W from global (L2-hot)
__global__ __launch_bounds__(512, 4) void tilegather_kernel(const unsigned* __restrict__ featbf,
                                                            const unsigned* __restrict__ edata,
                                                            const int* __restrict__ deg,
                                                            const int4* __restrict__ ovf,
                                                            const int* __restrict__ ovf_cnt,
                                                            const short* __restrict__ Wbf,
                                                            const float* __restrict__ b1,
                                                            const float* __restrict__ b2,
                                                            float* __restrict__ out,
                                                            int nNodes) {
    __shared__ float accp[2][16][64];             // 8 KB: [0]=lo dims, [1]=hi dims
    __shared__ __align__(16) unsigned sX[2][1024];// 8 KB
    __shared__ unsigned short entries[16 * CAP];  // 1 KB
    __shared__ int sdeg[16], sdd[16], pfx[17];

    int tid  = threadIdx.x;
    int lane = tid & 63;
    int w    = tid >> 6;
    int m0   = blockIdx.x * 16;

    // ---- p0: zero accum, load degrees ----
    {
        float* z = &accp[0][0][0];
        for (int i = tid; i < 2048; i += 512) z[i] = 0.0f;
        if (tid < 16) {
            int nd = m0 + tid;
            int d  = (nd < nNodes) ? deg[nd] : 0;
            sdeg[tid] = d;
            sdd[tid]  = d < CAP ? d : CAP;
        }
    }
    __syncthreads();

    // ---- p1: prefix + entry list ----
    if (tid == 0) {
        int s = 0;
        pfx[0] = 0;
#pragma unroll
        for (int i = 0; i < 16; i++) { s += sdd[i]; pfx[i + 1] = s; }
    }
    __syncthreads();
    int tot = pfx[16];
    if (tid < tot) {
        int lo = 0, hi = 16;
        while (hi - lo > 1) {
            int mid = (lo + hi) >> 1;
            if (tid >= pfx[mid]) lo = mid; else hi = mid;
        }
        entries[tid] = (unsigned short)((lo << 5) | (tid - pfx[lo]));
    }
    __syncthreads();

    // ---- p2: balanced edge drain ----
    {
        unsigned ebase = (unsigned)m0 << 5;
        int tm1 = tot - 1;
        for (int k0 = w * 8; k0 < tot; k0 += 64) {
            int ent[8];
            unsigned p[8], u[8];
#pragma unroll
            for (int t = 0; t < 8; t++) ent[t] = entries[min(k0 + t, tm1)];
#pragma unroll
            for (int t = 0; t < 8; t++) p[t] = edata[ebase + (unsigned)ent[t]];
#pragma unroll
            for (int t = 0; t < 8; t++)
                u[t] = featbf[(long)(p[t] >> 16) * (D / 2) + lane];
#pragma unroll
            for (int t = 0; t < 8; t++) {
                float v = (k0 + t < tot) ? bflo(p[t]) : 0.0f;
                int   n = ent[t] >> 5;
                atomicAdd(&accp[0][n][lane], bflo(u[t]) * v);
                atomicAdd(&accp[1][n][lane], bfhi(u[t]) * v);
            }
        }
    }
    __syncthreads();

    // ---- p3: overflow fixup (rare) ----
#pragma unroll
    for (int q = 0; q < 2; q++) {
        int n = w * 2 + q;
        if (sdeg[n] > CAP) {
            int node = m0 + n;
            int cnt  = *ovf_cnt;
            for (int basek = 0; basek < cnt; basek += 64) {
                int kk = basek + lane;
                int t  = (kk < cnt) ? ovf[kk].x : -1;
                unsigned long long mm = __ballot(t == node);
                while (mm) {
                    int b = __ffsll((long long)mm) - 1;
                    mm &= mm - 1;
                    int4  ov = ovf[basek + b];
                    float v  = __int_as_float(ov.z);
                    unsigned u = featbf[(long)ov.y * (D / 2) + lane];
                    atomicAdd(&accp[0][n][lane], bflo(u) * v);
                    atomicAdd(&accp[1][n][lane], bfhi(u) * v);
                }
            }
        }
    }
    __syncthreads();

    // ---- p4: pack X1/X2 into swizzled sX ----
#pragma unroll
    for (int q = 0; q < 2; q++) {
        int n    = w * 2 + q;
        int node = m0 + n;
        unsigned uf = featbf[(long)min(node, nNodes - 1) * (D / 2) + lane];
        float accx = accp[0][n][lane], accy = accp[1][n][lane];
        float fx = bflo(uf), fy = bfhi(uf);
        int idx = n * 64 + (((lane >> 2) ^ n) << 2) + (lane & 3);
        sX[0][idx] = packbf(fx + accx, fy + accy);
        sX[1][idx] = packbf(fx * accx, fy * accy);
    }
    __syncthreads();

    // ---- p5: GEMM, wave w = col-block w ----
    int mrow = lane & 15;
    int quad = lane >> 4;
    int o    = w * 16 + mrow;
    float bias = b1[o] + b2[o];

    v4f acc = (v4f)(0.0f);
#pragma unroll
    for (int s = 0; s < 4; s++) {
        int ck = s * 4 + quad;
        int pp = ck ^ mrow;
        short8 a1 = *(const short8*)(&sX[0][mrow * 64 + pp * 4]);
        short8 a2 = *(const short8*)(&sX[1][mrow * 64 + pp * 4]);
        const short* wp = Wbf + ck * 8;
        short8 w1 = *(const short8*)(wp + o * D);
        short8 w2 = *(const short8*)(wp + D * D + o * D);
        acc = __builtin_amdgcn_mfma_f32_16x16x32_bf16(a1, w1, acc, 0, 0, 0);
        acc = __builtin_amdgcn_mfma_f32_16x16x32_bf16(a2, w2, acc, 0, 0, 0);
    }

#pragma unroll
    for (int r = 0; r < 4; r++) {
        int node = m0 + quad * 4 + r;
        if (node < nNodes) {
            float v = acc[r] + bias;
            v = (v >= 0.0f) ? v : NEG_SLOPE * v;
            __builtin_nontemporal_store(v, &out[(long)node * D + o]);
        }
    }
}

extern "C" void kernel_launch(void* const* d_in, const int* in_sizes, int n_in,
                              void* d_out, int out_size, void* d_ws, size_t ws_size,
                              hipStream_t stream) {
    const float* feat = (const float*)d_in[0];
    const int*   tgt  = (const int*)d_in[1];
    const int*   nbr  = (const int*)d_in[2];
    const float* vals = (const float*)d_in[3];
    const float* W1   = (const float*)d_in[4];
    const float* b1   = (const float*)d_in[5];
    const float* W2   = (const float*)d_in[6];
    const float* b2   = (const float*)d_in[7];
    float*       out  = (float*)d_out;

    int E      = in_sizes[1];
    int nNodes = out_size / D;

    // ---- workspace layout ----
    int*      deg     = (int*)d_ws;                             // N (+4 incl ovf_cnt)
    int*      ovf_cnt = deg + nNodes;                           // 1 (inside memset range)
    int4*     ovf     = (int4*)(deg + nNodes + 4);              // E entries (16B-aligned)
    unsigned* edata   = (unsigned*)(ovf + E);                   // N*CAP u32
    short*    Wbf     = (short*)(edata + (long)nNodes * CAP);   // 2*D*D
    unsigned* featbf  = (unsigned*)(Wbf + 2 * D * D);           // N*D/2

    int nQuads = nNodes * (D / 4);
    int nbB    = (E + 256 * EPT - 1) / (256 * EPT);
    int nbC    = (nQuads + 255) / 256;

    hipMemsetAsync(deg, 0, (size_t)(nNodes + 4) * sizeof(int), stream);
    convbucket_kernel<<<nbB + nbC, 256, 0, stream>>>(feat, W1, W2, tgt, nbr, vals,
                                                     featbf, Wbf, deg, edata, ovf, ovf_cnt,
                                                     nQuads, E, nbB);

    int nTiles = (nNodes + 15) / 16;                  // 3125 blocks, 1 tile each
    tilegather_kernel<<<nTiles, 512, 0, stream>>>(featbf, edata, deg, ovf, ovf_cnt,
                                                  Wbf, b1, b2, out, nNodes);
}

// Round 7
// 173.473 us; speedup vs baseline: 3.3426x; 3.3426x over previous
//
#include <hip/hip_runtime.h>

#define D 128
#define CAP 32
#define EPT 4          // edges per thread in bucket blocks
#define NEG_SLOPE 0.01f

typedef float v4f __attribute__((ext_vector_type(4)));
typedef short short8 __attribute__((ext_vector_type(8)));

static __device__ __forceinline__ short f2bf(float f) {
    unsigned u = __float_as_uint(f);
    unsigned r = (u + 0x7fffu + ((u >> 16) & 1u)) >> 16;   // round-nearest-even
    return (short)r;
}
static __device__ __forceinline__ float bflo(unsigned u) { return __uint_as_float(u << 16); }
static __device__ __forceinline__ float bfhi(unsigned u) { return __uint_as_float(u & 0xffff0000u); }
static __device__ __forceinline__ unsigned packbf(float x, float y) {
    return (unsigned)(unsigned short)f2bf(x) | ((unsigned)(unsigned short)f2bf(y) << 16);
}

// -------- fused, block-specialized: bucket blocks + conv blocks ------------
// blocks [0, nbB)      : bucket fill, EPT edges/thread, packed 4-B entries
// blocks [nbB, ...)    : fp32->bf16 conversion stream (features + W)
__global__ __launch_bounds__(256) void convbucket_kernel(const float* __restrict__ feat,
                                                         const float* __restrict__ W1,
                                                         const float* __restrict__ W2,
                                                         const int* __restrict__ tgt,
                                                         const int* __restrict__ nbr,
                                                         const float* __restrict__ vals,
                                                         unsigned* __restrict__ featbf,
                                                         short* __restrict__ Wbf,
                                                         int* __restrict__ deg,
                                                         unsigned* __restrict__ edata,
                                                         int4* __restrict__ ovf,
                                                         int* __restrict__ ovf_cnt,
                                                         int nQuads, int E, int nbB) {
    if ((int)blockIdx.x < nbB) {
        // ---- bucket specialist: entry = (nbr<<16) | bf16(val) ----
        int base = (blockIdx.x * 256 + threadIdx.x) * EPT;
#pragma unroll
        for (int k = 0; k < EPT; k++) {
            int e = base + k;
            if (e < E) {
                int   t = __builtin_nontemporal_load(&tgt[e]);
                int   n = __builtin_nontemporal_load(&nbr[e]);
                float v = __builtin_nontemporal_load(&vals[e]);
                int slot = atomicAdd(&deg[t], 1);
                if (slot < CAP) {
                    unsigned ent = ((unsigned)n << 16) |
                                   (unsigned)(unsigned short)f2bf(v);
                    edata[((unsigned)t << 5) + slot] = ent;
                } else {
                    int o = atomicAdd(ovf_cnt, 1);
                    int4 ov;
                    ov.x = t;
                    ov.y = n;
                    ov.z = __float_as_int(v);
                    ov.w = 0;
                    ovf[o] = ov;
                }
            }
        }
    } else {
        // ---- conv specialist: float4 in, 2x packed bf16 out ----
        int i = (blockIdx.x - nbB) * 256 + threadIdx.x;
        if (i < nQuads) {
            v4f f = __builtin_nontemporal_load((const v4f*)feat + i);
            uint2 p;
            p.x = packbf(f.x, f.y);
            p.y = packbf(f.z, f.w);
            ((uint2*)featbf)[i] = p;
        }
        if (i < D * D) {
            Wbf[i]         = f2bf(W1[i]);
            Wbf[D * D + i] = f2bf(W2[i]);
        }
    }
}

// -------- gather + x1/x2 epilogue: one wave per node, uniform MLP-8 loop ---
// writes X1 = bf16(f + h), X2 = bf16(f * h) packed pairs
__global__ __launch_bounds__(256) void gather_kernel(const unsigned* __restrict__ featbf,
                                                     const unsigned* __restrict__ edata,
                                                     const int* __restrict__ deg,
                                                     const int4* __restrict__ ovf,
                                                     const int* __restrict__ ovf_cnt,
                                                     unsigned* __restrict__ X1,
                                                     unsigned* __restrict__ X2,
                                                     int nNodes) {
    int wid  = (blockIdx.x * 256 + threadIdx.x) >> 6;
    int lane = threadIdx.x & 63;
    if (wid >= nNodes) return;
    int d  = deg[wid];
    int dd = d < CAP ? d : CAP;   // edges present in edata

    unsigned uf = featbf[(long)wid * (D / 2) + lane];   // own row, hoisted

    float ax0 = 0.f, ay0 = 0.f, ax1 = 0.f, ay1 = 0.f;
    float ax2 = 0.f, ay2 = 0.f, ax3 = 0.f, ay3 = 0.f;

    {
        const unsigned* ep = edata + ((unsigned)wid << 5);
        int dm1 = dd - 1;
        // uniform loop: always 8 independent row loads in flight.
        for (int j = 0; j < dd; j += 8) {
            unsigned p0 = ep[min(j + 0, dm1)];
            unsigned p1 = ep[min(j + 1, dm1)];
            unsigned p2 = ep[min(j + 2, dm1)];
            unsigned p3 = ep[min(j + 3, dm1)];
            unsigned p4 = ep[min(j + 4, dm1)];
            unsigned p5 = ep[min(j + 5, dm1)];
            unsigned p6 = ep[min(j + 6, dm1)];
            unsigned p7 = ep[min(j + 7, dm1)];
            unsigned u0 = featbf[(long)(p0 >> 16) * (D / 2) + lane];
            unsigned u1 = featbf[(long)(p1 >> 16) * (D / 2) + lane];
            unsigned u2 = featbf[(long)(p2 >> 16) * (D / 2) + lane];
            unsigned u3 = featbf[(long)(p3 >> 16) * (D / 2) + lane];
            unsigned u4 = featbf[(long)(p4 >> 16) * (D / 2) + lane];
            unsigned u5 = featbf[(long)(p5 >> 16) * (D / 2) + lane];
            unsigned u6 = featbf[(long)(p6 >> 16) * (D / 2) + lane];
            unsigned u7 = featbf[(long)(p7 >> 16) * (D / 2) + lane];
            float v0 = (j + 0 < dd) ? bflo(p0) : 0.0f;
            float v1 = (j + 1 < dd) ? bflo(p1) : 0.0f;
            float v2 = (j + 2 < dd) ? bflo(p2) : 0.0f;
            float v3 = (j + 3 < dd) ? bflo(p3) : 0.0f;
            float v4 = (j + 4 < dd) ? bflo(p4) : 0.0f;
            float v5 = (j + 5 < dd) ? bflo(p5) : 0.0f;
            float v6 = (j + 6 < dd) ? bflo(p6) : 0.0f;
            float v7 = (j + 7 < dd) ? bflo(p7) : 0.0f;
            ax0 += bflo(u0) * v0; ay0 += bfhi(u0) * v0;
            ax1 += bflo(u1) * v1; ay1 += bfhi(u1) * v1;
            ax2 += bflo(u2) * v2; ay2 += bfhi(u2) * v2;
            ax3 += bflo(u3) * v3; ay3 += bfhi(u3) * v3;
            ax0 += bflo(u4) * v4; ay0 += bfhi(u4) * v4;
            ax1 += bflo(u5) * v5; ay1 += bfhi(u5) * v5;
            ax2 += bflo(u6) * v6; ay2 += bfhi(u6) * v6;
            ax3 += bflo(u7) * v7; ay3 += bfhi(u7) * v7;
        }
    }

    if (d > CAP) {
        // overflow edges live in the compact list (L2-hot, tiny)
        int cnt = *ovf_cnt;
        for (int basek = 0; basek < cnt; basek += 64) {
            int k = basek + lane;
            int t = (k < cnt) ? ovf[k].x : -1;
            unsigned long long m = __ballot(t == wid);
            while (m) {
                int b = __ffsll((long long)m) - 1;
                m &= m - 1;
                int4  ov = ovf[basek + b];
                float v  = __int_as_float(ov.z);
                unsigned u = featbf[(long)ov.y * (D / 2) + lane];
                ax0 += bflo(u) * v;
                ay0 += bfhi(u) * v;
            }
        }
    }

    float accx = (ax0 + ax1) + (ax2 + ax3);
    float accy = (ay0 + ay1) + (ay2 + ay3);
    float fx = bflo(uf), fy = bfhi(uf);
    X1[(long)wid * (D / 2) + lane] = packbf(fx + accx, fy + accy);
    X2[(long)wid * (D / 2) + lane] = packbf(fx * accx, fy * accy);
}

// -------- fused dual-GEMM + bias + leaky relu --------
// W staged in LDS (XOR-swizzled), amortized over 8 waves (512-thread block).
// One wave: 32 nodes x all 128 outs.
__global__ __launch_bounds__(512) void gemm_kernel(const short* __restrict__ X1s,
                                                   const short* __restrict__ X2s,
                                                   const short* __restrict__ Wbf,
                                                   const float* __restrict__ b1,
                                                   const float* __restrict__ b2,
                                                   float* __restrict__ out, int nNodes) {
    __shared__ __align__(16) short sW[2 * D * D];   // 64 KB

    int tid = threadIdx.x;
    // stage W: 4096 16-B chunks, XOR-swizzle chunk pos within row by row&15
    for (int c = tid; c < 4096; c += 512) {
        int r  = c >> 4;          // global row 0..255 (mat*128+row)
        int cc = c & 15;          // chunk within row
        int pp = cc ^ (r & 15);
        *(short8*)(&sW[r * D + pp * 8]) = *(const short8*)(Wbf + c * 8);
    }
    __syncthreads();

    int lane = tid & 63;
    int wid  = (blockIdx.x * 512 + tid) >> 6;
    int m0   = wid * 32;
    if (m0 >= nNodes) return;
    bool t2 = (m0 + 16) < nNodes;   // tiles are all-or-nothing (N % 16 == 0)

    int mrow = lane & 15;   // A: m index / B: n index / D: col index
    int quad = lane >> 4;   // A/B: k-group / D: row-group

    // bias is wave-invariant: hoist
    float bias[8];
#pragma unroll
    for (int ot = 0; ot < 8; ot++) {
        int o = ot * 16 + mrow;
        bias[ot] = b1[o] + b2[o];
    }

    const short* xa1 = X1s + (long)(m0 + mrow) * D + quad * 8;        // tile 0
    const short* xa2 = X2s + (long)(m0 + mrow) * D + quad * 8;
    const short* xb1 = xa1 + 16 * D;                                  // tile 1
    const short* xb2 = xa2 + 16 * D;

    v4f acc[2][8];
#pragma unroll
    for (int t = 0; t < 2; t++)
#pragma unroll
        for (int i = 0; i < 8; i++) acc[t][i] = (v4f)(0.0f);

#pragma unroll
    for (int s = 0; s < 4; s++) {
        short8 a1 = *(const short8*)(xa1 + s * 32);
        short8 a2 = *(const short8*)(xa2 + s * 32);
        short8 c1, c2;
        if (t2) {
            c1 = *(const short8*)(xb1 + s * 32);
            c2 = *(const short8*)(xb2 + s * 32);
        }
        int pp = (s * 4 + quad) ^ mrow;   // swizzled chunk
#pragma unroll
        for (int ot = 0; ot < 8; ot++) {
            int row = ot * 16 + mrow;
            short8 w1 = *(const short8*)(&sW[row * D + pp * 8]);
            short8 w2 = *(const short8*)(&sW[D * D + row * D + pp * 8]);
            acc[0][ot] = __builtin_amdgcn_mfma_f32_16x16x32_bf16(a1, w1, acc[0][ot], 0, 0, 0);
            acc[0][ot] = __builtin_amdgcn_mfma_f32_16x16x32_bf16(a2, w2, acc[0][ot], 0, 0, 0);
            if (t2) {
                acc[1][ot] = __builtin_amdgcn_mfma_f32_16x16x32_bf16(c1, w1, acc[1][ot], 0, 0, 0);
                acc[1][ot] = __builtin_amdgcn_mfma_f32_16x16x32_bf16(c2, w2, acc[1][ot], 0, 0, 0);
            }
        }
    }

#pragma unroll
    for (int ot = 0; ot < 8; ot++) {
        int o = ot * 16 + mrow;
#pragma unroll
        for (int r = 0; r < 4; r++) {
            int   node = m0 + quad * 4 + r;
            float v    = acc[0][ot][r] + bias[ot];
            v = (v >= 0.0f) ? v : NEG_SLOPE * v;
            __builtin_nontemporal_store(v, &out[(long)node * D + o]);
            if (t2) {
                float w2v = acc[1][ot][r] + bias[ot];
                w2v = (w2v >= 0.0f) ? w2v : NEG_SLOPE * w2v;
                __builtin_nontemporal_store(w2v, &out[(long)(node + 16) * D + o]);
            }
        }
    }
}

extern "C" void kernel_launch(void* const* d_in, const int* in_sizes, int n_in,
                              void* d_out, int out_size, void* d_ws, size_t ws_size,
                              hipStream_t stream) {
    const float* feat = (const float*)d_in[0];
    const int*   tgt  = (const int*)d_in[1];
    const int*   nbr  = (const int*)d_in[2];
    const float* vals = (const float*)d_in[3];
    const float* W1   = (const float*)d_in[4];
    const float* b1   = (const float*)d_in[5];
    const float* W2   = (const float*)d_in[6];
    const float* b2   = (const float*)d_in[7];
    float*       out  = (float*)d_out;

    int E      = in_sizes[1];
    int nNodes = out_size / D;

    // ---- workspace layout ----
    int*      deg     = (int*)d_ws;                             // N (+4 incl ovf_cnt)
    int*      ovf_cnt = deg + nNodes;                           // 1 (inside memset range)
    int4*     ovf     = (int4*)(deg + nNodes + 4);              // E entries (16B-aligned)
    unsigned* edata   = (unsigned*)(ovf + E);                   // N*CAP u32
    short*    Wbf     = (short*)(edata + (long)nNodes * CAP);   // 2*D*D
    unsigned* featbf  = (unsigned*)(Wbf + 2 * D * D);           // N*D/2
    unsigned* X1      = featbf + (long)nNodes * (D / 2);        // N*D/2
    unsigned* X2      = X1 + (long)nNodes * (D / 2);            // N*D/2

    int nQuads = nNodes * (D / 4);
    int nbB    = (E + 256 * EPT - 1) / (256 * EPT);   // 611 bucket blocks
    int nbC    = (nQuads + 255) / 256;                // 6250 conv blocks

    hipMemsetAsync(deg, 0, (size_t)(nNodes + 4) * sizeof(int), stream);
    convbucket_kernel<<<nbB + nbC, 256, 0, stream>>>(feat, W1, W2, tgt, nbr, vals,
                                                     featbf, Wbf, deg, edata, ovf, ovf_cnt,
                                                     nQuads, E, nbB);
    gather_kernel<<<(nNodes * 64 + 255) / 256, 256, 0, stream>>>(featbf, edata, deg, ovf, ovf_cnt,
                                                                 X1, X2, nNodes);

    int nPairTiles = (nNodes + 31) / 32;               // 1563
    int nBlocks    = (nPairTiles + 7) / 8;             // 196 blocks of 8 waves
    gemm_kernel<<<nBlocks, 512, 0, stream>>>((const short*)X1, (const short*)X2, Wbf, b1, b2, out, nNodes);
}

// Round 8
// 172.792 us; speedup vs baseline: 3.3558x; 1.0039x over previous
//
#include <hip/hip_runtime.h>

#define D 128
#define CAP 32
#define EPT 8          // edges per thread in bucket blocks
#define NEG_SLOPE 0.01f

typedef float v4f __attribute__((ext_vector_type(4)));
typedef short short8 __attribute__((ext_vector_type(8)));

static __device__ __forceinline__ short f2bf(float f) {
    unsigned u = __float_as_uint(f);
    unsigned r = (u + 0x7fffu + ((u >> 16) & 1u)) >> 16;   // round-nearest-even
    return (short)r;
}
static __device__ __forceinline__ float bflo(unsigned u) { return __uint_as_float(u << 16); }
static __device__ __forceinline__ float bfhi(unsigned u) { return __uint_as_float(u & 0xffff0000u); }
static __device__ __forceinline__ unsigned packbf(float x, float y) {
    return (unsigned)(unsigned short)f2bf(x) | ((unsigned)(unsigned short)f2bf(y) << 16);
}

// -------- fused, block-specialized: bucket blocks + conv blocks ------------
// blocks [0, nbB)      : bucket fill, EPT edges/thread, batched MLP pattern:
//                        load x8 -> atomic x8 (8 L2 RTs in flight) -> store x8
//                        deg is PADDED 1 int / 64-B line (16x less line pile-up)
// blocks [nbB, ...)    : fp32->bf16 conversion stream (features + W)
__global__ __launch_bounds__(256) void convbucket_kernel(const float* __restrict__ feat,
                                                         const float* __restrict__ W1,
                                                         const float* __restrict__ W2,
                                                         const int* __restrict__ tgt,
                                                         const int* __restrict__ nbr,
                                                         const float* __restrict__ vals,
                                                         unsigned* __restrict__ featbf,
                                                         short* __restrict__ Wbf,
                                                         int* __restrict__ deg,
                                                         unsigned* __restrict__ edata,
                                                         int4* __restrict__ ovf,
                                                         int* __restrict__ ovf_cnt,
                                                         int nPairs, int E, int nbB) {
    if ((int)blockIdx.x < nbB) {
        // ---- bucket specialist ----
        int base = (blockIdx.x * 256 + threadIdx.x) * EPT;
        int   tt[EPT], nn[EPT], slot[EPT];
        float vv[EPT];
#pragma unroll
        for (int k = 0; k < EPT; k++) {
            int e  = base + k;
            int ee = (e < E) ? e : (E - 1);
            tt[k] = tgt[ee];
            nn[k] = nbr[ee];
            vv[k] = vals[ee];
        }
#pragma unroll
        for (int k = 0; k < EPT; k++) {
            slot[k] = (base + k < E) ? atomicAdd(&deg[(unsigned)tt[k] << 4], 1) : CAP;
        }
#pragma unroll
        for (int k = 0; k < EPT; k++) {
            if (base + k < E) {
                if (slot[k] < CAP) {
                    unsigned ent = ((unsigned)nn[k] << 16) |
                                   (unsigned)(unsigned short)f2bf(vv[k]);
                    edata[((unsigned)tt[k] << 5) + slot[k]] = ent;
                } else {
                    int o = atomicAdd(ovf_cnt, 1);
                    int4 ov;
                    ov.x = tt[k];
                    ov.y = nn[k];
                    ov.z = __float_as_int(vv[k]);
                    ov.w = 0;
                    ovf[o] = ov;
                }
            }
        }
    } else {
        // ---- conv specialist: float2 in, packed bf16 pair out ----
        int i = (blockIdx.x - nbB) * 256 + threadIdx.x;
        if (i < nPairs) {
            float2 f = ((const float2*)feat)[i];
            featbf[i] = packbf(f.x, f.y);
        }
        if (i < D * D) {
            Wbf[i]         = f2bf(W1[i]);
            Wbf[D * D + i] = f2bf(W2[i]);
        }
    }
}

// -------- gather + x1/x2 epilogue: one wave per node, uniform MLP-8 loop ---
// writes X1 = bf16(f + h), X2 = bf16(f * h) packed pairs
__global__ __launch_bounds__(256) void gather_kernel(const unsigned* __restrict__ featbf,
                                                     const unsigned* __restrict__ edata,
                                                     const int* __restrict__ deg,
                                                     const int4* __restrict__ ovf,
                                                     const int* __restrict__ ovf_cnt,
                                                     unsigned* __restrict__ X1,
                                                     unsigned* __restrict__ X2,
                                                     int nNodes) {
    int wid  = (blockIdx.x * 256 + threadIdx.x) >> 6;
    int lane = threadIdx.x & 63;
    if (wid >= nNodes) return;
    int d  = deg[(unsigned)wid << 4];
    int dd = d < CAP ? d : CAP;   // edges present in edata

    unsigned uf = featbf[(long)wid * (D / 2) + lane];   // own row, hoisted

    float ax0 = 0.f, ay0 = 0.f, ax1 = 0.f, ay1 = 0.f;
    float ax2 = 0.f, ay2 = 0.f, ax3 = 0.f, ay3 = 0.f;

    {
        const unsigned* ep = edata + ((unsigned)wid << 5);
        int dm1 = dd - 1;
        // uniform loop: always 8 independent row loads in flight.
        for (int j = 0; j < dd; j += 8) {
            unsigned p0 = ep[min(j + 0, dm1)];
            unsigned p1 = ep[min(j + 1, dm1)];
            unsigned p2 = ep[min(j + 2, dm1)];
            unsigned p3 = ep[min(j + 3, dm1)];
            unsigned p4 = ep[min(j + 4, dm1)];
            unsigned p5 = ep[min(j + 5, dm1)];
            unsigned p6 = ep[min(j + 6, dm1)];
            unsigned p7 = ep[min(j + 7, dm1)];
            unsigned u0 = featbf[(long)(p0 >> 16) * (D / 2) + lane];
            unsigned u1 = featbf[(long)(p1 >> 16) * (D / 2) + lane];
            unsigned u2 = featbf[(long)(p2 >> 16) * (D / 2) + lane];
            unsigned u3 = featbf[(long)(p3 >> 16) * (D / 2) + lane];
            unsigned u4 = featbf[(long)(p4 >> 16) * (D / 2) + lane];
            unsigned u5 = featbf[(long)(p5 >> 16) * (D / 2) + lane];
            unsigned u6 = featbf[(long)(p6 >> 16) * (D / 2) + lane];
            unsigned u7 = featbf[(long)(p7 >> 16) * (D / 2) + lane];
            float v0 = (j + 0 < dd) ? bflo(p0) : 0.0f;
            float v1 = (j + 1 < dd) ? bflo(p1) : 0.0f;
            float v2 = (j + 2 < dd) ? bflo(p2) : 0.0f;
            float v3 = (j + 3 < dd) ? bflo(p3) : 0.0f;
            float v4 = (j + 4 < dd) ? bflo(p4) : 0.0f;
            float v5 = (j + 5 < dd) ? bflo(p5) : 0.0f;
            float v6 = (j + 6 < dd) ? bflo(p6) : 0.0f;
            float v7 = (j + 7 < dd) ? bflo(p7) : 0.0f;
            ax0 += bflo(u0) * v0; ay0 += bfhi(u0) * v0;
            ax1 += bflo(u1) * v1; ay1 += bfhi(u1) * v1;
            ax2 += bflo(u2) * v2; ay2 += bfhi(u2) * v2;
            ax3 += bflo(u3) * v3; ay3 += bfhi(u3) * v3;
            ax0 += bflo(u4) * v4; ay0 += bfhi(u4) * v4;
            ax1 += bflo(u5) * v5; ay1 += bfhi(u5) * v5;
            ax2 += bflo(u6) * v6; ay2 += bfhi(u6) * v6;
            ax3 += bflo(u7) * v7; ay3 += bfhi(u7) * v7;
        }
    }

    if (d > CAP) {
        // overflow edges live in the compact list (L2-hot, tiny)
        int cnt = *ovf_cnt;
        for (int basek = 0; basek < cnt; basek += 64) {
            int k = basek + lane;
            int t = (k < cnt) ? ovf[k].x : -1;
            unsigned long long m = __ballot(t == wid);
            while (m) {
                int b = __ffsll((long long)m) - 1;
                m &= m - 1;
                int4  ov = ovf[basek + b];
                float v  = __int_as_float(ov.z);
                unsigned u = featbf[(long)ov.y * (D / 2) + lane];
                ax0 += bflo(u) * v;
                ay0 += bfhi(u) * v;
            }
        }
    }

    float accx = (ax0 + ax1) + (ax2 + ax3);
    float accy = (ay0 + ay1) + (ay2 + ay3);
    float fx = bflo(uf), fy = bfhi(uf);
    X1[(long)wid * (D / 2) + lane] = packbf(fx + accx, fy + accy);
    X2[(long)wid * (D / 2) + lane] = packbf(fx * accx, fy * accy);
}

// -------- fused dual-GEMM + bias + leaky relu --------
// W staged in LDS (XOR-swizzled), amortized over 8 waves (512-thread block).
// One wave: 32 nodes x all 128 outs.
__global__ __launch_bounds__(512) void gemm_kernel(const short* __restrict__ X1s,
                                                   const short* __restrict__ X2s,
                                                   const short* __restrict__ Wbf,
                                                   const float* __restrict__ b1,
                                                   const float* __restrict__ b2,
                                                   float* __restrict__ out, int nNodes) {
    __shared__ __align__(16) short sW[2 * D * D];   // 64 KB

    int tid = threadIdx.x;
    // stage W: 4096 16-B chunks, XOR-swizzle chunk pos within row by row&15
    for (int c = tid; c < 4096; c += 512) {
        int r  = c >> 4;          // global row 0..255 (mat*128+row)
        int cc = c & 15;          // chunk within row
        int pp = cc ^ (r & 15);
        *(short8*)(&sW[r * D + pp * 8]) = *(const short8*)(Wbf + c * 8);
    }
    __syncthreads();

    int lane = tid & 63;
    int wid  = (blockIdx.x * 512 + tid) >> 6;
    int m0   = wid * 32;
    if (m0 >= nNodes) return;
    bool t2 = (m0 + 16) < nNodes;   // tiles are all-or-nothing (N % 16 == 0)

    int mrow = lane & 15;   // A: m index / B: n index / D: col index
    int quad = lane >> 4;   // A/B: k-group / D: row-group

    // bias is wave-invariant: hoist
    float bias[8];
#pragma unroll
    for (int ot = 0; ot < 8; ot++) {
        int o = ot * 16 + mrow;
        bias[ot] = b1[o] + b2[o];
    }

    const short* xa1 = X1s + (long)(m0 + mrow) * D + quad * 8;        // tile 0
    const short* xa2 = X2s + (long)(m0 + mrow) * D + quad * 8;
    const short* xb1 = xa1 + 16 * D;                                  // tile 1
    const short* xb2 = xa2 + 16 * D;

    v4f acc[2][8];
#pragma unroll
    for (int t = 0; t < 2; t++)
#pragma unroll
        for (int i = 0; i < 8; i++) acc[t][i] = (v4f)(0.0f);

#pragma unroll
    for (int s = 0; s < 4; s++) {
        short8 a1 = *(const short8*)(xa1 + s * 32);
        short8 a2 = *(const short8*)(xa2 + s * 32);
        short8 c1, c2;
        if (t2) {
            c1 = *(const short8*)(xb1 + s * 32);
            c2 = *(const short8*)(xb2 + s * 32);
        }
        int pp = (s * 4 + quad) ^ mrow;   // swizzled chunk
#pragma unroll
        for (int ot = 0; ot < 8; ot++) {
            int row = ot * 16 + mrow;
            short8 w1 = *(const short8*)(&sW[row * D + pp * 8]);
            short8 w2 = *(const short8*)(&sW[D * D + row * D + pp * 8]);
            acc[0][ot] = __builtin_amdgcn_mfma_f32_16x16x32_bf16(a1, w1, acc[0][ot], 0, 0, 0);
            acc[0][ot] = __builtin_amdgcn_mfma_f32_16x16x32_bf16(a2, w2, acc[0][ot], 0, 0, 0);
            if (t2) {
                acc[1][ot] = __builtin_amdgcn_mfma_f32_16x16x32_bf16(c1, w1, acc[1][ot], 0, 0, 0);
                acc[1][ot] = __builtin_amdgcn_mfma_f32_16x16x32_bf16(c2, w2, acc[1][ot], 0, 0, 0);
            }
        }
    }

#pragma unroll
    for (int ot = 0; ot < 8; ot++) {
        int o = ot * 16 + mrow;
#pragma unroll
        for (int r = 0; r < 4; r++) {
            int   node = m0 + quad * 4 + r;
            float v    = acc[0][ot][r] + bias[ot];
            v = (v >= 0.0f) ? v : NEG_SLOPE * v;
            __builtin_nontemporal_store(v, &out[(long)node * D + o]);
            if (t2) {
                float w2v = acc[1][ot][r] + bias[ot];
                w2v = (w2v >= 0.0f) ? w2v : NEG_SLOPE * w2v;
                __builtin_nontemporal_store(w2v, &out[(long)(node + 16) * D + o]);
            }
        }
    }
}

extern "C" void kernel_launch(void* const* d_in, const int* in_sizes, int n_in,
                              void* d_out, int out_size, void* d_ws, size_t ws_size,
                              hipStream_t stream) {
    const float* feat = (const float*)d_in[0];
    const int*   tgt  = (const int*)d_in[1];
    const int*   nbr  = (const int*)d_in[2];
    const float* vals = (const float*)d_in[3];
    const float* W1   = (const float*)d_in[4];
    const float* b1   = (const float*)d_in[5];
    const float* W2   = (const float*)d_in[6];
    const float* b2   = (const float*)d_in[7];
    float*       out  = (float*)d_out;

    int E      = in_sizes[1];
    int nNodes = out_size / D;

    // ---- workspace layout ----
    // deg padded: one counter per 64-B line => 16 ints per node
    int*      deg     = (int*)d_ws;                              // N*16 (+4 incl ovf_cnt)
    int*      ovf_cnt = deg + (long)nNodes * 16;                 // 1 (inside memset range)
    int4*     ovf     = (int4*)(deg + (long)nNodes * 16 + 4);    // E entries (16B-aligned)
    unsigned* edata   = (unsigned*)(ovf + E);                    // N*CAP u32
    short*    Wbf     = (short*)(edata + (long)nNodes * CAP);    // 2*D*D
    unsigned* featbf  = (unsigned*)(Wbf + 2 * D * D);            // N*D/2
    unsigned* X1      = featbf + (long)nNodes * (D / 2);         // N*D/2
    unsigned* X2      = X1 + (long)nNodes * (D / 2);             // N*D/2

    int nPairs = nNodes * (D / 2);
    int nbB    = (E + 256 * EPT - 1) / (256 * EPT);   // 306 bucket blocks
    int nbC    = (nPairs + 255) / 256;                // 12500 conv blocks

    hipMemsetAsync(deg, 0, ((size_t)nNodes * 16 + 4) * sizeof(int), stream);
    convbucket_kernel<<<nbB + nbC, 256, 0, stream>>>(feat, W1, W2, tgt, nbr, vals,
                                                     featbf, Wbf, deg, edata, ovf, ovf_cnt,
                                                     nPairs, E, nbB);
    gather_kernel<<<(nNodes * 64 + 255) / 256, 256, 0, stream>>>(featbf, edata, deg, ovf, ovf_cnt,
                                                                 X1, X2, nNodes);

    int nPairTiles = (nNodes + 31) / 32;               // 1563
    int nBlocks    = (nPairTiles + 7) / 8;             // 196 blocks of 8 waves
    gemm_kernel<<<nBlocks, 512, 0, stream>>>((const short*)X1, (const short*)X2, Wbf, b1, b2, out, nNodes);
}